// Round 12
// baseline (429.324 us; speedup 1.0000x reference)
//
#include <hip/hip_runtime.h>
#include <hip/hip_bf16.h>
#include <math.h>

typedef __bf16 bf16_t;
typedef __bf16 bf16x8 __attribute__((ext_vector_type(8)));
typedef float f32x4 __attribute__((ext_vector_type(4)));

// Problem dims
#define NPH 12288          // B*P = B*H
#define SIM_B (384*384)
#define EMB_B (384*512)

// d_out offsets (floats)
#define OUT_LOGITS 0
#define OUT_PROBS 96
#define OUT_H2P 192
#define OUT_P2H (192 + 32*384*384)

// ws offsets (bytes)
#define OFF_WATH 0L
#define OFF_WATL 524288L
#define OFF_WCT  1048576L
#define OFF_A    2097152L          // 50 MB region, 4 x 6291456 bf16 elems
#define OFF_SIM  52428800L         // 18.9 MB f32
#define OFF_CM   71303168L
#define OFF_CS   (OFF_CM + 49152L)
#define OFF_GP   (OFF_CS + 49152L)
#define OFF_H    (OFF_GP + 524288L)

// element offsets within region A (bf16 elems)
#define PROJ_LO   6291456L         // lo offset from hi (also batch-block size)
#define PROJ_Z    12582912L        // proj z-stride (p -> h)
#define ATT_ALL_E 12582912L        // att_all elem base in region A
#define CMP_Z     6291456L

#define BM 128
#define BN 128
#define BKK 32

#define M_PROJ   0   // A: f32 reg-stage split; B: bf16 hi/lo gload; 3-pass
#define M_SPLITB 1   // A,B: bf16 hi/lo gload; 3-pass
#define M_PLAIN  2   // A: f32 reg-stage hi; B: bf16 gload; 1-pass
#define M_CONCAT 3   // A: k<K1 f32 reg-stage hi else bf16 gload; B: bf16 gload
#define O_F32   0
#define O_BF16  1
#define O_SPLIT 2
#define O_GSUM  3    // no C store; masked row-sum partials -> Gp (Cf)

__device__ inline void gload16(const void* g, void* l) {
    __builtin_amdgcn_global_load_lds(
        (const __attribute__((address_space(1))) void*)g,
        (__attribute__((address_space(3))) void*)l, 16, 0, 0);
}

// Swizzled reg-stage: 16 consecutive f32 -> bf16 hi (+lo) into LDS row `row`,
// chunks c0,c0+1 stored at chunk^((row>>1)&3)  [bank-conflict-free read layout]
template<bool SPLIT>
__device__ inline void stage_sw(const float* __restrict__ s,
                                bf16_t* hi, bf16_t* lo, int row, int c0)
{
    float xs[16];
    *(float4*)&xs[0]  = *(const float4*)(s);
    *(float4*)&xs[4]  = *(const float4*)(s + 4);
    *(float4*)&xs[8]  = *(const float4*)(s + 8);
    *(float4*)&xs[12] = *(const float4*)(s + 12);
    bf16x8 h0, h1, l0, l1;
    #pragma unroll
    for (int i = 0; i < 8; i++) {
        float x = xs[i];     bf16_t hh = (bf16_t)x; h0[i] = hh;
        float y = xs[i + 8]; bf16_t hy = (bf16_t)y; h1[i] = hy;
        if (SPLIT) { l0[i] = (bf16_t)(x - (float)hh); l1[i] = (bf16_t)(y - (float)hy); }
    }
    const int key = (row >> 1) & 3;
    const int cc0 = c0 ^ key, cc1 = cc0 ^ 1;
    *(bf16x8*)&hi[row * 32 + cc0 * 8] = h0;
    *(bf16x8*)&hi[row * 32 + cc1 * 8] = h1;
    if (SPLIT) {
        *(bf16x8*)&lo[row * 32 + cc0 * 8] = l0;
        *(bf16x8*)&lo[row * 32 + cc1 * 8] = l1;
    }
}

// Unified MFMA GEMM: C[m][n] = sum_k A[m][k] * B'[n][k]  (NT, k-contig)
// Block IDs XCD-chunk swizzled. KSPLIT: z = batch*2+half, K halves atomicAdd'd.
template<int MODE, int OUTK, bool BIAS, bool RELU, bool KSPLIT = false>
__global__ __launch_bounds__(256) void mgemm(
    const float* __restrict__ Af, const float* __restrict__ Af2, int zalt,
    const bf16_t* __restrict__ Abh, long loA,
    const bf16_t* __restrict__ A2b, long a2B,
    const bf16_t* __restrict__ Bbh, long loB,
    const float* __restrict__ bias,
    const int* __restrict__ pmask, const int* __restrict__ hmask,
    float* __restrict__ Cf, bf16_t* __restrict__ Cb, long loC,
    int K, int K1,
    long aB, long bB, long cB,
    int lda, int lda2, int ldb, int ldc)
{
    constexpr int NS = (MODE == M_PROJ || MODE == M_SPLITB) ? 2 : 1;
    constexpr bool REPACK = (OUTK == O_SPLIT || OUTK == O_BF16);
    constexpr int SM_ELEMS = REPACK ? ((NS * 8192 > 17408) ? NS * 8192 : 17408)
                                    : NS * 8192;
    __shared__ bf16_t smem[SM_ELEMS];
    bf16_t* As = smem;                 // [NS][4096]
    bf16_t* Bs = smem + NS * 4096;     // [NS][4096]

    const int tid = threadIdx.x;

    // ---- XCD-chunked block swizzle (bijective: all grids are %8 == 0) ----
    const int gx = gridDim.x, gy = gridDim.y;
    const int nwg = gx * gy * gridDim.z;
    int flat = blockIdx.x + gx * (blockIdx.y + gy * blockIdx.z);
    flat = (flat & 7) * (nwg >> 3) + (flat >> 3);
    const int bz_ = flat / (gx * gy);
    const int rem_ = flat - bz_ * (gx * gy);
    const int by_ = rem_ / gx, bx_ = rem_ - by_ * gx;

    const long z = bz_;
    const long zb = KSPLIT ? (z >> 1) : z;
    const int koff = KSPLIT ? (int)(z & 1) * K : 0;
    const int m0 = by_ * BM, n0 = bx_ * BN;

    const float* Afs = (MODE == M_PROJ || MODE == M_PLAIN || MODE == M_CONCAT)
                       ? ((zb >= zalt) ? Af2 : Af) : nullptr;

    // reg-stage map (f32): 128 rows x 32 k, 16 elems/thread
    const int sr = tid >> 1, sc = (tid & 1) * 16, c0 = (tid & 1) * 2;
    // gload map: rows gr, gr+64; source chunk pre-swizzled
    const int gr = tid >> 2;
    const int gco = ((tid & 3) ^ ((gr >> 1) & 3)) * 8;
    const int wlds = (tid >> 6) * 512;

    const int l = tid & 63;
    const int wv = tid >> 6;
    const int wr = (wv >> 1) * 64, wc = (wv & 1) * 64;
    const int fr = l & 15, fq = l >> 4;

    f32x4 acc[4][4] = {};

    for (int k0 = 0; k0 < K; k0 += BKK) {
        const int kk = koff + k0;
        // ---- stage A ----
        if (MODE == M_PROJ || MODE == M_PLAIN) {
            const float* s = Afs + zb * aB + (long)(m0 + sr) * lda + kk + sc;
            stage_sw<MODE == M_PROJ>(s, As, As + (NS - 1) * 4096, sr, c0);
        } else if (MODE == M_CONCAT) {
            if (k0 < K1) {
                const float* s = Afs + zb * aB + (long)(m0 + sr) * lda + kk + sc;
                stage_sw<false>(s, As, nullptr, sr, c0);
            } else {
                const bf16_t* s = A2b + zb * a2B + (long)(m0 + gr) * lda2 + (kk - K1) + gco;
                gload16(s, As + wlds);
                gload16(s + (long)64 * lda2, As + 2048 + wlds);
            }
        } else { // M_SPLITB
            const bf16_t* s = Abh + zb * aB + (long)(m0 + gr) * lda + kk + gco;
            gload16(s, As + wlds);
            gload16(s + (long)64 * lda, As + 2048 + wlds);
            gload16(s + loA, As + (NS - 1) * 4096 + wlds);
            gload16(s + loA + (long)64 * lda, As + (NS - 1) * 4096 + 2048 + wlds);
        }
        // ---- stage B (always bf16 gload) ----
        {
            const bf16_t* s = Bbh + zb * bB + (long)(n0 + gr) * ldb + kk + gco;
            gload16(s, Bs + wlds);
            gload16(s + (long)64 * ldb, Bs + 2048 + wlds);
            if (NS == 2) {
                gload16(s + loB, Bs + (NS - 1) * 4096 + wlds);
                gload16(s + loB + (long)64 * ldb, Bs + (NS - 1) * 4096 + 2048 + wlds);
            }
        }
        __syncthreads();

        // ---- fragments (swizzled reads) + MFMA ----
        bf16x8 a_h[4], b_h[4], a_l[4], b_l[4];
        #pragma unroll
        for (int i = 0; i < 4; i++) {
            const int ra = wr + i * 16 + fr;
            const int rb = wc + i * 16 + fr;
            const int ka = (fq ^ ((ra >> 1) & 3)) * 8;
            const int kb = (fq ^ ((rb >> 1) & 3)) * 8;
            a_h[i] = *(const bf16x8*)&As[ra * 32 + ka];
            b_h[i] = *(const bf16x8*)&Bs[rb * 32 + kb];
            if (NS == 2) {
                a_l[i] = *(const bf16x8*)&As[(NS - 1) * 4096 + ra * 32 + ka];
                b_l[i] = *(const bf16x8*)&Bs[(NS - 1) * 4096 + rb * 32 + kb];
            }
        }
        #pragma unroll
        for (int mi = 0; mi < 4; mi++)
            #pragma unroll
            for (int ni = 0; ni < 4; ni++) {
                acc[mi][ni] = __builtin_amdgcn_mfma_f32_16x16x32_bf16(a_h[mi], b_h[ni], acc[mi][ni], 0, 0, 0);
                if (NS == 2) {
                    acc[mi][ni] = __builtin_amdgcn_mfma_f32_16x16x32_bf16(a_h[mi], b_l[ni], acc[mi][ni], 0, 0, 0);
                    acc[mi][ni] = __builtin_amdgcn_mfma_f32_16x16x32_bf16(a_l[mi], b_h[ni], acc[mi][ni], 0, 0, 0);
                }
            }
        __syncthreads();
    }

    // ---- epilogue ----
    if constexpr (OUTK == O_GSUM) {
        // masked row-sum: Gp[pc][b][zb*512 + col] = sum_rows relu(acc+bias)*mask
        __shared__ float red[8][128];
        __shared__ int smask[128];
        const int* mrow = (zb >= zalt) ? hmask : pmask;
        const int bb = m0 / 384;
        const int brow0 = m0 - bb * 384;
        if (tid < 128) smask[tid] = mrow[bb * 384 + brow0 + tid];
        __syncthreads();
        const int rid = (wv >> 1) * 4 + fq;
        #pragma unroll
        for (int ni = 0; ni < 4; ni++) {
            const int c = wc + ni * 16 + fr;
            const float bv = bias[n0 + c];
            float local = 0.f;
            #pragma unroll
            for (int mi = 0; mi < 4; mi++)
                #pragma unroll
                for (int j = 0; j < 4; j++) {
                    const int rloc = wr + mi * 16 + fq * 4 + j;
                    float v = fmaxf(acc[mi][ni][j] + bv, 0.f);
                    local += v * (float)smask[rloc];
                }
            red[rid][c] = local;
        }
        __syncthreads();
        if (tid < 128) {
            float s = 0.f;
            #pragma unroll
            for (int r = 0; r < 8; r++) s += red[r][tid];
            const int pc = (m0 >> 7) % 3;
            Cf[((long)pc * 32 + bb) * 1024 + zb * 512 + n0 + tid] = s;
        }
    } else if constexpr (REPACK) {
        // LDS-repack epilogue: coalesced bf16x8 stores (rows stride 136 elems)
        const int prow = tid >> 1;          // 0..127
        const int pcol0 = (tid & 1) * 64;
        #pragma unroll
        for (int r = 0; r < (OUTK == O_SPLIT ? 2 : 1); r++) {
            __syncthreads();
            #pragma unroll
            for (int ni = 0; ni < 4; ni++) {
                const int c = wc + ni * 16 + fr;
                const float bv = BIAS ? bias[n0 + c] : 0.f;
                #pragma unroll
                for (int mi = 0; mi < 4; mi++)
                    #pragma unroll
                    for (int j = 0; j < 4; j++) {
                        const int row = wr + mi * 16 + fq * 4 + j;
                        float v = acc[mi][ni][j] + bv;
                        if (RELU) v = fmaxf(v, 0.f);
                        bf16_t h = (bf16_t)v;
                        smem[row * 136 + c] = (r == 0) ? h : (bf16_t)(v - (float)h);
                    }
            }
            __syncthreads();
            #pragma unroll
            for (int i = 0; i < 8; i++) {
                bf16x8 w = *(const bf16x8*)&smem[prow * 136 + pcol0 + i * 8];
                *(bf16x8*)&Cb[zb * cB + (long)(m0 + prow) * ldc + n0 + pcol0 + i * 8
                              + (r ? loC : 0L)] = w;
            }
        }
    } else { // O_F32 (plain store, or atomic-accumulate under KSPLIT)
        #pragma unroll
        for (int ni = 0; ni < 4; ni++) {
            const int col = n0 + wc + ni * 16 + fr;
            const float bv = BIAS ? bias[col] : 0.f;
            #pragma unroll
            for (int mi = 0; mi < 4; mi++) {
                #pragma unroll
                for (int j = 0; j < 4; j++) {
                    const int row = m0 + wr + mi * 16 + fq * 4 + j;
                    float v = acc[mi][ni][j] + bv;
                    if (RELU) v = fmaxf(v, 0.f);
                    const long idx = zb * cB + (long)row * ldc + col;
                    if (KSPLIT) atomicAdd(&Cf[idx], v);
                    else        Cf[idx] = v;
                }
            }
        }
    }
}

// out[c][r] = bf16(in[r][c]) (+ optional lo split); z-select between in/in2
template<bool SPLIT>
__global__ __launch_bounds__(256) void transpose_kernel(
    const float* __restrict__ in, const float* __restrict__ in2, int zsplit,
    bf16_t* __restrict__ out, bf16_t* __restrict__ outLo,
    int R, int C, long inB, long outB)
{
    __shared__ float tile[32][33];
    const int z = blockIdx.z;
    const float* src = (z >= zsplit) ? (in2 + (long)(z - zsplit) * inB)
                                     : (in + (long)z * inB);
    const int x0 = blockIdx.x * 32, y0 = blockIdx.y * 32;
    const int tx = threadIdx.x & 31, ty = threadIdx.x >> 5;
    #pragma unroll
    for (int i = 0; i < 32; i += 8)
        tile[ty + i][tx] = src[(long)(y0 + ty + i) * C + x0 + tx];
    __syncthreads();
    bf16_t* dst = out + (long)z * outB;
    bf16_t* dstL = SPLIT ? (outLo + (long)z * outB) : nullptr;
    #pragma unroll
    for (int i = 0; i < 32; i += 8) {
        float v = tile[tx][ty + i];
        bf16_t h = (bf16_t)v;
        dst[(long)(x0 + ty + i) * R + y0 + tx] = h;
        if (SPLIT) dstL[(long)(x0 + ty + i) * R + y0 + tx] = (bf16_t)(v - (float)h);
    }
}

// Row-wise masked softmax over sim rows (AllenNLP legacy semantics).
__global__ __launch_bounds__(384) void masked_softmax_row(
    const float* __restrict__ S, const int* __restrict__ mask,
    float* __restrict__ out)
{
    const int row = blockIdx.x;        // b*384 + p
    const int b = row / 384;
    const int t = threadIdx.x;         // h
    __shared__ float redmax[6], redsum[6];

    float v = S[(long)row * 384 + t];
    int mm = mask[b * 384 + t];

    float x = mm ? v : -3.4e38f;
    #pragma unroll
    for (int o = 32; o > 0; o >>= 1) x = fmaxf(x, __shfl_xor(x, o, 64));
    int wid = t >> 6, lane = t & 63;
    if (lane == 0) redmax[wid] = x;
    __syncthreads();
    float mx = redmax[0];
    #pragma unroll
    for (int w = 1; w < 6; w++) mx = fmaxf(mx, redmax[w]);

    float e = mm ? expf(v - mx) : 0.f;
    float s = e;
    #pragma unroll
    for (int o = 32; o > 0; o >>= 1) s += __shfl_xor(s, o, 64);
    if (lane == 0) redsum[wid] = s;
    __syncthreads();
    float tot = 0.f;
    #pragma unroll
    for (int w = 0; w < 6; w++) tot += redsum[w];

    out[(long)row * 384 + t] = (tot > 0.f) ? e / tot : 0.f;
}

// Column softmax pass 1: max-then-sum. grid (6 hc, 32 b), block 256.
__global__ __launch_bounds__(256) void col_stats(
    const float* __restrict__ S, const int* __restrict__ mask,
    float* __restrict__ cmax, float* __restrict__ csum)
{
    __shared__ int pml[384];
    __shared__ float mred[4][64], sred[4][64];
    const int b = blockIdx.y;
    const int h0 = blockIdx.x * 64;
    const int t = threadIdx.x;
    const int tk = t >> 6, hh = t & 63;

    for (int i = t; i < 384; i += 256) pml[i] = mask[b * 384 + i];
    __syncthreads();

    const float* Sb = S + (long)b * SIM_B + h0 + hh;
    float m = -3.4e38f;
    for (int p = tk; p < 384; p += 4)
        if (pml[p]) m = fmaxf(m, Sb[(long)p * 384]);
    mred[tk][hh] = m;
    __syncthreads();
    const float M = fmaxf(fmaxf(mred[0][hh], mred[1][hh]),
                          fmaxf(mred[2][hh], mred[3][hh]));
    float s = 0.f;
    for (int p = tk; p < 384; p += 4)
        if (pml[p]) s += expf(Sb[(long)p * 384] - M);
    sred[tk][hh] = s;
    __syncthreads();
    if (t < 64) {
        const float Mf = fmaxf(fmaxf(mred[0][t], mred[1][t]),
                               fmaxf(mred[2][t], mred[3][t]));
        cmax[b * 384 + h0 + t] = Mf;
        csum[b * 384 + h0 + t] = sred[0][t] + sred[1][t] + sred[2][t] + sred[3][t];
    }
}

// Column softmax pass 2: fused transpose + normalize. out[b][h][p].
__global__ __launch_bounds__(256) void col_write(
    const float* __restrict__ S, const int* __restrict__ mask,
    const float* __restrict__ cmax, const float* __restrict__ csum,
    float* __restrict__ out)
{
    __shared__ float tile[32][33];
    const int b = blockIdx.z;
    const int h0 = blockIdx.x * 32, p0 = blockIdx.y * 32;
    const int tx = threadIdx.x & 31, ty = threadIdx.x >> 5;
    const float* src = S + (long)b * SIM_B;
    #pragma unroll
    for (int i = 0; i < 32; i += 8)
        tile[ty + i][tx] = src[(long)(p0 + ty + i) * 384 + h0 + tx];
    __syncthreads();
    const int pm_v = mask[b * 384 + p0 + tx];
    float* dst = out + (long)b * SIM_B;
    #pragma unroll
    for (int i = 0; i < 32; i += 8) {
        const int h = h0 + ty + i;
        const float mx = cmax[b * 384 + h];
        const float tot = csum[b * 384 + h];
        float v = tile[tx][ty + i];
        float r = (pm_v && tot > 0.f) ? expf(v - mx) / tot : 0.f;
        dst[(long)h * 384 + p0 + tx] = r;
    }
}

// hidden = relu(G @ W1 + b1), combining 3 p-chunk partials. grid (8 jc, 32 b)
__global__ __launch_bounds__(256) void hidden_kernel(
    const float* __restrict__ Gp, const float* __restrict__ W1,
    const float* __restrict__ b1, float* __restrict__ Hbuf)
{
    __shared__ float g[1024];
    __shared__ float part[4][64];
    const int b = blockIdx.y, j0 = blockIdx.x * 64;
    const int t = threadIdx.x;
    for (int i = t; i < 1024; i += 256)
        g[i] = Gp[((long)0 * 32 + b) * 1024 + i] + Gp[((long)1 * 32 + b) * 1024 + i]
             + Gp[((long)2 * 32 + b) * 1024 + i];
    __syncthreads();
    const int tj = t & 63, tk = t >> 6;
    const float* w = W1 + (long)(tk * 256) * 512 + j0 + tj;
    const float* gk = g + tk * 256;
    float acc = 0.f;
    #pragma unroll 8
    for (int k = 0; k < 256; k++)
        acc = fmaf(gk[k], w[(long)k * 512], acc);
    part[tk][tj] = acc;
    __syncthreads();
    if (t < 64) {
        float v = part[0][t] + part[1][t] + part[2][t] + part[3][t] + b1[j0 + t];
        Hbuf[(long)b * 512 + j0 + t] = fmaxf(v, 0.f);
    }
}

// logits + probs: grid 32, block 64
__global__ __launch_bounds__(64) void logits_kernel(
    const float* __restrict__ Hbuf, const float* __restrict__ W2,
    const float* __restrict__ b2, float* __restrict__ out)
{
    const int b = blockIdx.x, l = threadIdx.x;
    const float* h = Hbuf + (long)b * 512;
    float a0 = 0.f, a1 = 0.f, a2 = 0.f;
    #pragma unroll
    for (int k = l; k < 512; k += 64) {
        float hv = h[k];
        a0 = fmaf(hv, W2[k * 3 + 0], a0);
        a1 = fmaf(hv, W2[k * 3 + 1], a1);
        a2 = fmaf(hv, W2[k * 3 + 2], a2);
    }
    #pragma unroll
    for (int o = 32; o > 0; o >>= 1) {
        a0 += __shfl_xor(a0, o, 64);
        a1 += __shfl_xor(a1, o, 64);
        a2 += __shfl_xor(a2, o, 64);
    }
    if (l == 0) {
        float l0 = a0 + b2[0], l1 = a1 + b2[1], l2 = a2 + b2[2];
        float mx = fmaxf(l0, fmaxf(l1, l2));
        float e0 = expf(l0 - mx), e1 = expf(l1 - mx), e2 = expf(l2 - mx);
        float s = e0 + e1 + e2;
        out[OUT_LOGITS + b * 3 + 0] = l0;
        out[OUT_LOGITS + b * 3 + 1] = l1;
        out[OUT_LOGITS + b * 3 + 2] = l2;
        out[OUT_PROBS + b * 3 + 0] = e0 / s;
        out[OUT_PROBS + b * 3 + 1] = e1 / s;
        out[OUT_PROBS + b * 3 + 2] = e2 / s;
    }
}

extern "C" void kernel_launch(void* const* d_in, const int* in_sizes, int n_in,
                              void* d_out, int out_size, void* d_ws, size_t ws_size,
                              hipStream_t stream) {
    const float* emb_p = (const float*)d_in[0];
    const float* emb_h = (const float*)d_in[1];
    const int* pm = (const int*)d_in[2];
    const int* hm = (const int*)d_in[3];
    const float* Wa = (const float*)d_in[4];
    const float* ba = (const float*)d_in[5];
    const float* Wc = (const float*)d_in[6];
    const float* bc = (const float*)d_in[7];
    const float* W1 = (const float*)d_in[8];
    const float* b1 = (const float*)d_in[9];
    const float* W2 = (const float*)d_in[10];
    const float* b2 = (const float*)d_in[11];
    float* out = (float*)d_out;
    char* W = (char*)d_ws;

    bf16_t* WaTh  = (bf16_t*)(W + OFF_WATH);   // [512a][512d] hi
    bf16_t* WaTl  = (bf16_t*)(W + OFF_WATL);   // lo
    bf16_t* WcT   = (bf16_t*)(W + OFF_WCT);    // [512n][1024k]
    bf16_t* A     = (bf16_t*)(W + OFF_A);      // 50 MB region
    float*  sim   = (float*)(W + OFF_SIM);
    float*  cmaxb = (float*)(W + OFF_CM);
    float*  csumb = (float*)(W + OFF_CS);
    float*  Gp    = (float*)(W + OFF_GP);      // [3][32][1024] f32
    float*  Hbuf  = (float*)(W + OFF_H);
    // region-A aliases (lifetime-disjoint)
    bf16_t* projs  = A;                        // [hi_p|lo_p|hi_h|lo_h] x 6291456
    bf16_t* embT   = A;                        // [64][512][384] (p batches 0-31, h 32-63)
    bf16_t* attAll = A + ATT_ALL_E;            // [64][384][512] (attp 0-31, atth 32-63)

    // 0: weight transposes (WaT split bf16, WcT bf16)
    transpose_kernel<true><<<dim3(16, 16, 1), 256, 0, stream>>>(
        Wa, nullptr, 999, WaTh, WaTl, 512, 512, 0, 0);
    transpose_kernel<false><<<dim3(16, 32, 1), 256, 0, stream>>>(
        Wc, nullptr, 999, WcT, nullptr, 1024, 512, 0, 0);

    // 1: proj merged (z=0 premise, z=1 hypothesis), split bf16 output
    mgemm<M_PROJ, O_SPLIT, true, true><<<dim3(4, 96, 2), 256, 0, stream>>>(
        emb_p, emb_h, 1, nullptr, 0, nullptr, 0, WaTh, 262144L, ba,
        nullptr, nullptr,
        nullptr, projs, PROJ_LO,
        512, 0, 0L, 0L, PROJ_Z, 512, 0, 512, 512);

    // 2: sim (batched NT, hi/lo 3-pass, all-gload), 2-way K-split + atomics
    hipMemsetAsync(sim, 0, 18874368L, stream);
    mgemm<M_SPLITB, O_F32, false, false, true><<<dim3(3, 3, 64), 256, 0, stream>>>(
        nullptr, nullptr, 999, projs, PROJ_LO, nullptr, 0,
        projs + PROJ_Z, PROJ_LO, nullptr,
        nullptr, nullptr,
        sim, nullptr, 0,
        256, 0, (long)EMB_B, (long)EMB_B, (long)SIM_B, 512, 0, 512, 384);

    // 3: p2h row softmax -> d_out
    masked_softmax_row<<<NPH, 384, 0, stream>>>(sim, hm, out + OUT_P2H);
    // 4: h2p column softmax (stats + fused transpose write)
    col_stats<<<dim3(6, 32), 256, 0, stream>>>(sim, pm, cmaxb, csumb);
    col_write<<<dim3(12, 12, 32), 256, 0, stream>>>(sim, pm, cmaxb, csumb, out + OUT_H2P);

    // 5: emb transposes merged -> embT (z<32: emb_p, z>=32: emb_h)
    transpose_kernel<false><<<dim3(16, 12, 64), 256, 0, stream>>>(
        emb_p, emb_h, 32, embT, nullptr, 384, 512, (long)EMB_B, (long)EMB_B);

    // 6: attention apply merged: z<32: attp = h2p@embTp ; z>=32: atth = p2h@embTh
    mgemm<M_PLAIN, O_BF16, false, false><<<dim3(4, 3, 64), 256, 0, stream>>>(
        out + OUT_H2P, nullptr, 1 << 30, nullptr, 0, nullptr, 0,
        embT, 0, nullptr,
        nullptr, nullptr,
        nullptr, attAll, 0,
        384, 0, (long)SIM_B, (long)EMB_B, (long)EMB_B, 384, 0, 384, 512);

    // 7: cmp merged + fused masked row-sum -> Gp partials (no cmp store)
    //    z=0: relu(cat(emb_p, atth)@Wc+bc) . pm ; z=1: cat(emb_h, attp) . hm
    mgemm<M_CONCAT, O_GSUM, true, true><<<dim3(4, 96, 2), 256, 0, stream>>>(
        emb_p, emb_h, 1, nullptr, 0,
        attAll + CMP_Z, -(long)CMP_Z,       // z=0 -> atth, z=1 -> attp
        WcT, 0, bc,
        pm, hm,
        Gp, nullptr, 0,
        1024, 512, 0L, 0L, 0L, 512, 512, 1024, 512);

    // 8: aggregate MLP + softmax
    hidden_kernel<<<dim3(8, 32), 256, 0, stream>>>(Gp, W1, b1, Hbuf);
    logits_kernel<<<32, 64, 0, stream>>>(Hbuf, W2, b2, out);
}